// Round 18
// baseline (67.707 us; speedup 1.0000x reference)
//
#include <hip/hip_runtime.h>
#include <hip/hip_bf16.h>

#define NB   1024
#define NT   256
#define BTOT 262144   // NB*NT == B

typedef __attribute__((ext_vector_type(8))) short short8;
typedef __attribute__((ext_vector_type(4))) float f32x4;

__device__ __forceinline__ float relu_(float x) { return fmaxf(x, 0.0f); }

// setup-kernel-only (portable RNE)
__device__ __forceinline__ short f2bf(float x) {
    unsigned u = __float_as_uint(x);
    return (short)((u + 0x7FFFu + ((u >> 16) & 1u)) >> 16);
}
__device__ __forceinline__ unsigned pk2bf(float a, float b) {
    return ((unsigned)(unsigned short)f2bf(a)) |
           (((unsigned)(unsigned short)f2bf(b)) << 16);
}

// hot-path conversions: native casts -> HW v_cvt_pk_bf16_f32
__device__ __forceinline__ unsigned pkbf(float a, float b) {
    __hip_bfloat162 h = __float22bfloat162_rn(make_float2(a, b));
    return *(unsigned*)&h;
}
__device__ __forceinline__ void st_bf16(unsigned char* p, float x) {
    *(__hip_bfloat16*)p = __float2bfloat16(x);
}
__device__ __forceinline__ short8 pack8(float a0,float a1,float a2,float a3,
                                        float a4,float a5,float a6,float a7) {
    uint4 v = make_uint4(pkbf(a0,a1), pkbf(a2,a3), pkbf(a4,a5), pkbf(a6,a7));
    return *(short8*)&v;
}

// d_ws byte map:
//  0    : (reserved) | A0 packed bf16 pairs at dword 160
//  768  : 46 B-fragments x 512 shorts (bf16); K-axes PHYSICALLY PERMUTED to
//         writer-thread-contiguous LDS slot order
//  47872: partials [NB*12] f32
#define A0_DW    160
#define FRAGS_BYTE 768
#define PART_BYTE 47872
#define NFRAG 46

__global__ __launch_bounds__(256) void kp_setup(
    const float* __restrict__ w1, const float* __restrict__ b1,
    const float* __restrict__ g1, const float* __restrict__ bt1,
    const float* __restrict__ m1, const float* __restrict__ v1,
    const float* __restrict__ w2, const float* __restrict__ b2,
    const float* __restrict__ g2, const float* __restrict__ bt2,
    const float* __restrict__ m2, const float* __restrict__ v2,
    const float* __restrict__ w3, const float* __restrict__ b3,
    const float* __restrict__ g3, const float* __restrict__ bt3,
    const float* __restrict__ m3, const float* __restrict__ v3,
    const float* __restrict__ fw1, const float* __restrict__ fb1,
    const float* __restrict__ fw2, const float* __restrict__ fb2,
    float* __restrict__ wsB, short* __restrict__ frags)
{
    __shared__ float w1f[180], b1f[10], a0f[10];
    __shared__ float w2f[400], b2f[20];
    __shared__ float w3f[1200], b3f[30];
    const int t = threadIdx.x;

    if (t < 10) {
        float s = g1[t] * rsqrtf(v1[t] + 1e-5f);
        float bb = (b1[t] - m1[t]) * s + bt1[t];
        b1f[t] = bb; a0f[t] = relu_(bb);
        for (int i = 0; i < 18; ++i) w1f[t * 18 + i] = w1[t * 18 + i] * s;
    } else if (t >= 64 && t < 84) {
        int o = t - 64;
        float s = g2[o] * rsqrtf(v2[o] + 1e-5f);
        b2f[o] = (b2[o] - m2[o]) * s + bt2[o];
        for (int i = 0; i < 20; ++i) w2f[o * 20 + i] = w2[o * 20 + i] * s;
    } else if (t >= 128 && t < 158) {
        int o = t - 128;
        float s = g3[o] * rsqrtf(v3[o] + 1e-5f);
        b3f[o] = (b3[o] - m3[o]) * s + bt3[o];
        for (int i = 0; i < 40; ++i) w3f[o * 40 + i] = w3[o * 40 + i] * s;
    }
    __syncthreads();

    if (blockIdx.x == 0 && t < 5)
        ((unsigned*)wsB)[A0_DW + t] = pk2bf(a0f[2 * t], a0f[2 * t + 1]);

    for (int e = blockIdx.x * 256 + t; e < NFRAG * 512; e += gridDim.x * 256) {
        int frag = e >> 9, l = (e >> 3) & 63, j = e & 7;
        float val = 0.f;
        if (frag < 4) {                       // conv1: logical K (unchanged), N=20
            int p = frag, nt = p >> 1, kt = p & 1;
            int k = kt * 32 + (l >> 4) * 8 + j, n = nt * 16 + (l & 15);
            if (n < 20) {
                int o = n % 10, pp = n / 10;
                if (k < 36) { int i = k >> 1, s = k & 1; if (s == pp) val = w1f[o * 18 + i]; }
                else if (k == 36) val = b1f[o];
            }
        } else if (frag < 12) {               // conv2: a1 PHYSICAL slots
            int p = frag - 4, nt_ = p >> 1, kt = p & 1;
            int kp = kt * 32 + (l >> 4) * 8 + j, n = nt_ * 16 + (l & 15);
            if (n < 60) {
                int lk = -1;
                if (kp < 32) { int s = kp & 1, r = kp >> 1;
                               lk = (s == 0) ? 10 + r : (r < 4 ? 26 + r : -1); }
                else if (kp < 42) lk = kp - 32;
                else if (kp < 52) lk = 30 + (kp - 42);
                else if (kp == 52) lk = 40;
                if (lk >= 0) {
                    int q = n / 20, o = n % 20;
                    if (lk < 40) { int pp = lk / 10, i = lk % 10, d = pp - q;
                                   if (d == 0 || d == 1) val = w2f[o * 20 + i * 2 + d]; }
                    else val = b2f[o];
                }
            }
        } else if (frag < 20) {               // conv3: a2 PHYSICAL p=lrow*4+nt
            int p = frag - 12, nt_ = p >> 1, kt = p & 1;
            int kp = kt * 32 + (l >> 4) * 8 + j, n = nt_ * 16 + (l & 15);
            if (n < 60) {
                int n2 = 16 * (kp & 3) + (kp >> 2);
                int q = n / 30, o = n % 30;
                if (n2 < 60) { int pp = n2 / 20, i = n2 % 20, d = pp - q;
                               if (d == 0 || d == 1) val = w3f[o * 40 + i * 2 + d]; }
                else if (n2 == 60) val = b3f[o];
            }
        } else if (frag < 34) {               // fc1: f PHYSICAL p=lrow*4+nt
            int p = frag - 20, n7 = p >> 1, kt = p & 1;
            int kp = kt * 32 + (l >> 4) * 8 + j, col = n7 * 16 + (l & 15);
            if (col < 100) {
                int n3 = 16 * (kp & 3) + (kp >> 2);
                if (n3 < 60) { int kf = 2 * (n3 % 30) + (n3 / 30);
                               val = fw1[col * 60 + kf]; }
                else if (n3 == 60) val = fb1[col];
            }
        } else {                              // fc2: z PHYSICAL p=lrow*4+nn (per half)
            int p = frag - 34, n3_ = p >> 2, kt = p & 3;
            int kp = kt * 32 + (l >> 4) * 8 + j, col = n3_ * 16 + (l & 15);
            if (col < 36) {
                int jj = 64 * (kp >> 6) + 16 * ((kp & 63) & 3) + ((kp & 63) >> 2);
                if (jj < 100) val = fw2[col * 100 + jj];
                else if (jj == 100) val = fb2[col];
            }
        }
        frags[e] = f2bf(val);
    }
}

__global__ __launch_bounds__(NT) void kp_main(
    const float* __restrict__ cin, const int* __restrict__ tmask,
    const float* __restrict__ wsB, const short* __restrict__ frags,
    float* __restrict__ xout, float* __restrict__ missout,
    float* __restrict__ partials)
{
    // 59392 B total -> 2 blocks/CU (8 waves/CU); VGPR budget relaxed to 256
    __shared__ __align__(16) unsigned char sOUT[NT * 88];       // out rows, bf16
    __shared__ __align__(16) unsigned char sT1[4 * 2 * 16 * 144]; // a1, 2 tiles/wave
    __shared__ __align__(16) unsigned char sT2[4 * 2 * 16 * 144]; // a2/f/z, 2 tiles

    const int t = threadIdx.x;
    const int lane = t & 63, wave = t >> 6;
    const unsigned lrow = (unsigned)(lane & 15);
    const unsigned lkg  = (unsigned)(lane >> 4);
    const unsigned wbase = (unsigned)(t & ~63);
    const short8* frg = (const short8*)frags;

    unsigned char* T1 = sT1 + wave * 4608;   // [2 tiles][16 rows][144 B]
    unsigned char* T2 = sT2 + wave * 4608;

    // ---- one-time: T1 constant region in BOTH tiles (slots 32..63) ----
    {
        const unsigned* a0p = (const unsigned*)wsB + A0_DW;
        uint4 A0q = *(const uint4*)a0p;
        unsigned A0e = a0p[4];
        if (lane < 32) {
            unsigned char* b = &T1[(unsigned)(lane >> 4) * 2304u
                                   + (unsigned)(lane & 15) * 144u + 64u];
            *(uint4*)(b +  0) = A0q;
            *(uint4*)(b + 16) = make_uint4(A0e, A0q.x, A0q.y, A0q.z);
            *(uint4*)(b + 32) = make_uint4(A0q.w, A0e, 0x00003F80u, 0u);
            *(uint4*)(b + 48) = make_uint4(0u, 0u, 0u, 0u);
        }
    }

    #pragma unroll 1
    for (int m = 0; m < 2; ++m) {
        const unsigned Rb0 = wbase + 32u * (unsigned)m;
        const unsigned Rb1 = Rb0 + 16u;
        unsigned char* T1a = T1;             unsigned char* T1b = T1 + 2304;
        unsigned char* T2a = T2;             unsigned char* T2b = T2 + 2304;

        // ---- conv1 A-frags for both tiles straight from global ----
        const float* cra = cin + (size_t)(blockIdx.x * NT + Rb0 + lrow) * 36;
        const float* crb = cin + (size_t)(blockIdx.x * NT + Rb1 + lrow) * 36;
        float4 a0 = *(const float4*)(cra + 8 * lkg);
        float4 a1_ = *(const float4*)(cra + 8 * lkg + 4);
        float4 a2_ = *(const float4*)(cra + 32);
        float4 b0_ = *(const float4*)(crb + 8 * lkg);
        float4 b1_ = *(const float4*)(crb + 8 * lkg + 4);
        float4 b2_ = *(const float4*)(crb + 32);
        float sf = (lkg == 0u) ? 1.f : 0.f;
        short8 Aa0 = pack8(a0.x, a0.y, a0.z, a0.w, a1_.x, a1_.y, a1_.z, a1_.w);
        short8 Ab0 = pack8(a2_.x*sf, a2_.y*sf, a2_.z*sf, a2_.w*sf, sf, 0.f, 0.f, 0.f);
        short8 Aa1 = pack8(b0_.x, b0_.y, b0_.z, b0_.w, b1_.x, b1_.y, b1_.z, b1_.w);
        short8 Ab1 = pack8(b2_.x*sf, b2_.y*sf, b2_.z*sf, b2_.w*sf, sf, 0.f, 0.f, 0.f);

        // ---- conv1 -> a1 (frags loaded ONCE, used by both tiles) ----
        {
            f32x4 Da[2], Db[2];
            #pragma unroll
            for (int nt = 0; nt < 2; ++nt) {
                short8 f0 = frg[(nt * 2 + 0) * 64 + lane];
                short8 f1 = frg[(nt * 2 + 1) * 64 + lane];
                Da[nt] = (f32x4){0.f,0.f,0.f,0.f};
                Da[nt] = __builtin_amdgcn_mfma_f32_16x16x32_bf16(Aa0, f0, Da[nt], 0,0,0);
                Da[nt] = __builtin_amdgcn_mfma_f32_16x16x32_bf16(Ab0, f1, Da[nt], 0,0,0);
                Db[nt] = (f32x4){0.f,0.f,0.f,0.f};
                Db[nt] = __builtin_amdgcn_mfma_f32_16x16x32_bf16(Aa1, f0, Db[nt], 0,0,0);
                Db[nt] = __builtin_amdgcn_mfma_f32_16x16x32_bf16(Ab1, f1, Db[nt], 0,0,0);
            }
            #pragma unroll
            for (int i = 0; i < 4; ++i) {
                *(unsigned*)&T1a[(4 * lkg + i) * 144 + lrow * 4] =
                    pkbf(relu_(Da[0][i]), relu_(Da[1][i]));
                *(unsigned*)&T1b[(4 * lkg + i) * 144 + lrow * 4] =
                    pkbf(relu_(Db[0][i]), relu_(Db[1][i]));
            }
        }

        // ---- conv2 ----
        Aa0 = *(const short8*)&T1a[lrow * 144 + lkg * 16u];
        Ab0 = *(const short8*)&T1a[lrow * 144 + 64u + lkg * 16u];
        Aa1 = *(const short8*)&T1b[lrow * 144 + lkg * 16u];
        Ab1 = *(const short8*)&T1b[lrow * 144 + 64u + lkg * 16u];
        {
            f32x4 Da[4], Db[4];
            #pragma unroll
            for (int nt = 0; nt < 4; ++nt) {
                short8 f0 = frg[(4 + nt * 2 + 0) * 64 + lane];
                short8 f1 = frg[(4 + nt * 2 + 1) * 64 + lane];
                Da[nt] = (f32x4){0.f,0.f,0.f,0.f};
                Da[nt] = __builtin_amdgcn_mfma_f32_16x16x32_bf16(Aa0, f0, Da[nt], 0,0,0);
                Da[nt] = __builtin_amdgcn_mfma_f32_16x16x32_bf16(Ab0, f1, Da[nt], 0,0,0);
                Db[nt] = (f32x4){0.f,0.f,0.f,0.f};
                Db[nt] = __builtin_amdgcn_mfma_f32_16x16x32_bf16(Aa1, f0, Db[nt], 0,0,0);
                Db[nt] = __builtin_amdgcn_mfma_f32_16x16x32_bf16(Ab1, f1, Db[nt], 0,0,0);
            }
            #pragma unroll
            for (int i = 0; i < 4; ++i) {
                float ea = (lrow == 12u) ? 1.0f : relu_(Da[3][i]);
                float eb = (lrow == 12u) ? 1.0f : relu_(Db[3][i]);
                *(uint2*)&T2a[(4 * lkg + i) * 144 + lrow * 8] =
                    make_uint2(pkbf(relu_(Da[0][i]), relu_(Da[1][i])),
                               pkbf(relu_(Da[2][i]), ea));
                *(uint2*)&T2b[(4 * lkg + i) * 144 + lrow * 8] =
                    make_uint2(pkbf(relu_(Db[0][i]), relu_(Db[1][i])),
                               pkbf(relu_(Db[2][i]), eb));
            }
        }

        // ---- conv3 ----
        Aa0 = *(const short8*)&T2a[lrow * 144 + lkg * 16u];
        Ab0 = *(const short8*)&T2a[lrow * 144 + 64u + lkg * 16u];
        Aa1 = *(const short8*)&T2b[lrow * 144 + lkg * 16u];
        Ab1 = *(const short8*)&T2b[lrow * 144 + 64u + lkg * 16u];
        {
            f32x4 Da[4], Db[4];
            #pragma unroll
            for (int nt = 0; nt < 4; ++nt) {
                short8 f0 = frg[(12 + nt * 2 + 0) * 64 + lane];
                short8 f1 = frg[(12 + nt * 2 + 1) * 64 + lane];
                Da[nt] = (f32x4){0.f,0.f,0.f,0.f};
                Da[nt] = __builtin_amdgcn_mfma_f32_16x16x32_bf16(Aa0, f0, Da[nt], 0,0,0);
                Da[nt] = __builtin_amdgcn_mfma_f32_16x16x32_bf16(Ab0, f1, Da[nt], 0,0,0);
                Db[nt] = (f32x4){0.f,0.f,0.f,0.f};
                Db[nt] = __builtin_amdgcn_mfma_f32_16x16x32_bf16(Aa1, f0, Db[nt], 0,0,0);
                Db[nt] = __builtin_amdgcn_mfma_f32_16x16x32_bf16(Ab1, f1, Db[nt], 0,0,0);
            }
            #pragma unroll
            for (int i = 0; i < 4; ++i) {
                float ea = (lrow == 12u) ? 1.0f : relu_(Da[3][i]);
                float eb = (lrow == 12u) ? 1.0f : relu_(Db[3][i]);
                *(uint2*)&T2a[(4 * lkg + i) * 144 + lrow * 8] =
                    make_uint2(pkbf(relu_(Da[0][i]), relu_(Da[1][i])),
                               pkbf(relu_(Da[2][i]), ea));
                *(uint2*)&T2b[(4 * lkg + i) * 144 + lrow * 8] =
                    make_uint2(pkbf(relu_(Db[0][i]), relu_(Db[1][i])),
                               pkbf(relu_(Db[2][i]), eb));
            }
        }

        // ---- fc1 + fc2 ----
        short8 Fa0 = *(const short8*)&T2a[lrow * 144 + lkg * 16u];
        short8 Fb0 = *(const short8*)&T2a[lrow * 144 + 64u + lkg * 16u];
        short8 Fa1 = *(const short8*)&T2b[lrow * 144 + lkg * 16u];
        short8 Fb1 = *(const short8*)&T2b[lrow * 144 + 64u + lkg * 16u];
        f32x4 acc2a[3], acc2b[3];
        #pragma unroll
        for (int n = 0; n < 3; ++n) {
            acc2a[n] = (f32x4){0.f,0.f,0.f,0.f};
            acc2b[n] = (f32x4){0.f,0.f,0.f,0.f};
        }

        #pragma unroll
        for (int h = 0; h < 2; ++h) {
            #pragma unroll
            for (int pr = 0; pr < 2; ++pr) {
                const int n0 = 4 * h + 2 * pr;
                const int n1 = n0 + 1;
                short8 f00 = frg[(20 + n0 * 2 + 0) * 64 + lane];
                short8 f01 = frg[(20 + n0 * 2 + 1) * 64 + lane];
                f32x4 vaA = (f32x4){0.f,0.f,0.f,0.f}, vaB = vaA;
                vaA = __builtin_amdgcn_mfma_f32_16x16x32_bf16(Fa0, f00, vaA, 0,0,0);
                vaA = __builtin_amdgcn_mfma_f32_16x16x32_bf16(Fb0, f01, vaA, 0,0,0);
                vaB = __builtin_amdgcn_mfma_f32_16x16x32_bf16(Fa1, f00, vaB, 0,0,0);
                vaB = __builtin_amdgcn_mfma_f32_16x16x32_bf16(Fb1, f01, vaB, 0,0,0);
                f32x4 vbA = (f32x4){0.f,0.f,0.f,0.f}, vbB = vbA;
                if (n1 < 7) {
                    short8 f10 = frg[(20 + n1 * 2 + 0) * 64 + lane];
                    short8 f11 = frg[(20 + n1 * 2 + 1) * 64 + lane];
                    vbA = __builtin_amdgcn_mfma_f32_16x16x32_bf16(Fa0, f10, vbA, 0,0,0);
                    vbA = __builtin_amdgcn_mfma_f32_16x16x32_bf16(Fb0, f11, vbA, 0,0,0);
                    vbB = __builtin_amdgcn_mfma_f32_16x16x32_bf16(Fa1, f10, vbB, 0,0,0);
                    vbB = __builtin_amdgcn_mfma_f32_16x16x32_bf16(Fb1, f11, vbB, 0,0,0);
                }
                #pragma unroll
                for (int i = 0; i < 4; ++i) {
                    float z0a = relu_(vaA[i]), z0b = relu_(vaB[i]);
                    if (h == 1 && pr == 1 && lrow == 4u) { z0a = 1.0f; z0b = 1.0f; }
                    float z1a = (n1 < 7) ? relu_(vbA[i]) : 0.f;
                    float z1b = (n1 < 7) ? relu_(vbB[i]) : 0.f;
                    *(unsigned*)&T2a[(4 * lkg + i) * 144 + lrow * 8 + 4 * pr] = pkbf(z0a, z1a);
                    *(unsigned*)&T2b[(4 * lkg + i) * 144 + lrow * 8 + 4 * pr] = pkbf(z0b, z1b);
                }
            }
            #pragma unroll
            for (int q = 0; q < 2; ++q) {
                const int kt = 2 * h + q;
                short8 AzA = *(const short8*)&T2a[lrow * 144 + (unsigned)(q * 64) + lkg * 16u];
                short8 AzB = *(const short8*)&T2b[lrow * 144 + (unsigned)(q * 64) + lkg * 16u];
                #pragma unroll
                for (int n = 0; n < 3; ++n) {
                    short8 fz = frg[(34 + n * 4 + kt) * 64 + lane];
                    acc2a[n] = __builtin_amdgcn_mfma_f32_16x16x32_bf16(AzA, fz, acc2a[n], 0,0,0);
                    acc2b[n] = __builtin_amdgcn_mfma_f32_16x16x32_bf16(AzB, fz, acc2b[n], 0,0,0);
                }
            }
        }

        // out (bf16) -> sOUT rows of both tiles
        #pragma unroll
        for (int n = 0; n < 3; ++n) {
            const int col = 16 * n + (int)lrow;
            if (col < 36) {
                #pragma unroll
                for (int i = 0; i < 4; ++i) {
                    st_bf16(&sOUT[(Rb0 + 4 * lkg + i) * 88 + col * 2], acc2a[n][i]);
                    st_bf16(&sOUT[(Rb1 + 4 * lkg + i) * 88 + col * 2], acc2b[n][i]);
                }
            }
        }
    }

    // ---- part losses, minimal live set: on-demand loads ----
    const float* cp = cin + (size_t)(blockIdx.x * NT + t) * 36;
    float sp[5], np[5];
    {   // head (0,14,15); gt mixes x[:,15,0] and c[:,15,1] (faithful)
        unsigned w0  = *(const unsigned*)&sOUT[t * 88 + 0];
        unsigned w28 = *(const unsigned*)&sOUT[t * 88 + 56];
        unsigned w30 = *(const unsigned*)&sOUT[t * 88 + 60];
        float o0x = __uint_as_float(w0 << 16),  o0y = __uint_as_float(w0 & 0xFFFF0000u);
        float o28 = __uint_as_float(w28 << 16), o29 = __uint_as_float(w28 & 0xFFFF0000u);
        float o30 = __uint_as_float(w30 << 16), o31 = __uint_as_float(w30 & 0xFFFF0000u);
        float2 c0  = *(const float2*)(cp + 0);
        float2 c28 = *(const float2*)(cp + 28);
        float2 c30 = *(const float2*)(cp + 30);
        float dxa = o0x - o28, dya = o0y - o29;
        float dxb = o0x - o30, dyb = o0y - o31;
        float pred = 0.5f * (sqrtf(dxa*dxa + dya*dya) + sqrtf(dxb*dxb + dyb*dyb));
        float cxa = c0.x - c28.x, cya = c0.y - c28.y;
        float gxa = c0.x - o30,   gya = c0.y - c30.y;
        float gt = 0.5f * (sqrtf(cxa*cxa + cya*cya) + sqrtf(gxa*gxa + gya*gya));
        float vf = (c0.x != -1.f && c28.x != -1.f && c30.x != -1.f) ? 1.f : 0.f;
        float e = pred - gt;
        sp[0] = e * e * vf; np[0] = vf;
    }
    #pragma unroll
    for (int p = 0; p < 4; ++p) {
        const int a = 2 + 3 * p;   // b=a+1, cc=a+2
        unsigned wA = *(const unsigned*)&sOUT[t * 88 + 4 * a + 0];
        unsigned wB = *(const unsigned*)&sOUT[t * 88 + 4 * a + 4];
        unsigned wC = *(const unsigned*)&sOUT[t * 88 + 4 * a + 8];
        float oax = __uint_as_float(wA << 16), oay = __uint_as_float(wA & 0xFFFF0000u);
        float obx = __uint_as_float(wB << 16), oby = __uint_as_float(wB & 0xFFFF0000u);
        float ocx = __uint_as_float(wC << 16), ocy = __uint_as_float(wC & 0xFFFF0000u);
        float2 ca = *(const float2*)(cp + 2 * a);
        float2 cb = *(const float2*)(cp + 2 * a + 2);
        float2 cc2 = *(const float2*)(cp + 2 * a + 4);
        float dxa = oax - obx, dya = oay - oby;
        float dxb = obx - ocx, dyb = oby - ocy;
        float pred = 0.5f * (sqrtf(dxa*dxa + dya*dya) + sqrtf(dxb*dxb + dyb*dyb));
        float cxa = ca.x - cb.x, cya = ca.y - cb.y;
        float gxa = cb.x - ocx,  gya = cb.y - cc2.y;
        float gt = 0.5f * (sqrtf(cxa*cxa + cya*cya) + sqrtf(gxa*gxa + gya*gya));
        float vf = (ca.x != -1.f && cb.x != -1.f && cc2.x != -1.f) ? 1.f : 0.f;
        float e = pred - gt;
        sp[p + 1] = e * e * vf; np[p + 1] = vf;
    }

    __syncthreads();   // all waves' out-rows complete

    // ---- coalesced x store + miss store + elementwise kp-loss ----
    const size_t blkBase = (size_t)blockIdx.x * (NT * 36);
    const float4* cin4 = (const float4*)(cin + blkBase);
    const int4*   tm4  = (const int4*)(tmask + blkBase);
    float4*       x4   = (float4*)(xout + blkBase);
    float*        mo   = missout + blkBase;

    float s1 = 0.f, s2 = 0.f;
    #pragma unroll
    for (int i = 0; i < 9; ++i) {
        int g4 = i * NT + t;
        unsigned g = 4u * (unsigned)g4;
        unsigned row = g / 36u;
        unsigned col = g - row * 36u;          // col % 4 == 0 -> 8B aligned
        uint2 w = *(const uint2*)&sOUT[row * 88u + col * 2u];
        float4 xv;
        xv.x = __uint_as_float(w.x << 16);
        xv.y = __uint_as_float(w.x & 0xFFFF0000u);
        xv.z = __uint_as_float(w.y << 16);
        xv.w = __uint_as_float(w.y & 0xFFFF0000u);
        float4 cv = cin4[g4];
        int4   mv = tm4[g4];
        x4[g4] = xv;
        mo[g + 0] = (cv.x != -1.f) ? 1.f : 0.f;
        mo[g + 1] = (cv.y != -1.f) ? 1.f : 0.f;
        mo[g + 2] = (cv.z != -1.f) ? 1.f : 0.f;
        mo[g + 3] = (cv.w != -1.f) ? 1.f : 0.f;
        float m0 = (float)mv.x, m1_ = (float)mv.y, m2_ = (float)mv.z, m3_ = (float)mv.w;
        float d0 = xv.x - cv.x, d1 = xv.y - cv.y, d2 = xv.z - cv.z, d3 = xv.w - cv.w;
        s1 += d0*d0*m0 + d1*d1*m1_ + d2*d2*m2_ + d3*d3*m3_;
        s2 += m0 + m1_ + m2_ + m3_;
    }

    // ---- block reduction of 12 scalars (scratch = dead sT1 region) ----
    float rv[12] = { s1, s2, sp[0], np[0], sp[1], np[1],
                     sp[2], np[2], sp[3], np[3], sp[4], np[4] };
    #pragma unroll
    for (int v = 0; v < 12; ++v) {
        #pragma unroll
        for (int off = 32; off > 0; off >>= 1)
            rv[v] += __shfl_down(rv[v], off, 64);
    }
    if (lane == 0) {
        float* sw = (float*)(sT1 + wave * 4608);
        #pragma unroll
        for (int v = 0; v < 12; ++v) sw[v] = rv[v];
    }
    __syncthreads();
    if (t < 12) {
        float s = 0.f;
        #pragma unroll
        for (int w = 0; w < 4; ++w) s += ((const float*)(sT1 + w * 4608))[t];
        partials[blockIdx.x * 12 + t] = s;
    }
}

__global__ __launch_bounds__(256) void kp_fin(const float* __restrict__ partials,
                                              float* __restrict__ total_out)
{
    __shared__ float sred[4][12];
    const int t = threadIdx.x;
    float rv[12];
    #pragma unroll
    for (int v = 0; v < 12; ++v) rv[v] = 0.f;
    for (int b = t; b < NB; b += 256) {
        #pragma unroll
        for (int v = 0; v < 12; ++v) rv[v] += partials[b * 12 + v];
    }
    #pragma unroll
    for (int v = 0; v < 12; ++v) {
        #pragma unroll
        for (int off = 32; off > 0; off >>= 1)
            rv[v] += __shfl_down(rv[v], off, 64);
    }
    const int wave = t >> 6, lane = t & 63;
    if (lane == 0) {
        #pragma unroll
        for (int v = 0; v < 12; ++v) sred[wave][v] = rv[v];
    }
    __syncthreads();
    if (t == 0) {
        float acc[12];
        #pragma unroll
        for (int v = 0; v < 12; ++v)
            acc[v] = sred[0][v] + sred[1][v] + sred[2][v] + sred[3][v];
        float total = acc[0] / acc[1];
        #pragma unroll
        for (int p = 0; p < 5; ++p) {
            float s = acc[2 + 2 * p], n = acc[3 + 2 * p];
            total += (n > 0.f) ? (s / fmaxf(n, 1.f)) : 0.f;
        }
        total_out[0] = total;
    }
}

extern "C" void kernel_launch(void* const* d_in, const int* in_sizes, int n_in,
                              void* d_out, int out_size, void* d_ws, size_t ws_size,
                              hipStream_t stream)
{
    const float* cin   = (const float*)d_in[0];
    const int*   tmask = (const int*)  d_in[1];
    const float* w1  = (const float*)d_in[2];
    const float* b1  = (const float*)d_in[3];
    const float* g1  = (const float*)d_in[4];
    const float* bt1 = (const float*)d_in[5];
    const float* m1  = (const float*)d_in[6];
    const float* v1  = (const float*)d_in[7];
    const float* w2  = (const float*)d_in[8];
    const float* b2  = (const float*)d_in[9];
    const float* g2  = (const float*)d_in[10];
    const float* bt2 = (const float*)d_in[11];
    const float* m2  = (const float*)d_in[12];
    const float* v2  = (const float*)d_in[13];
    const float* w3  = (const float*)d_in[14];
    const float* b3  = (const float*)d_in[15];
    const float* g3  = (const float*)d_in[16];
    const float* bt3 = (const float*)d_in[17];
    const float* m3  = (const float*)d_in[18];
    const float* v3  = (const float*)d_in[19];
    const float* fw1 = (const float*)d_in[20];
    const float* fb1 = (const float*)d_in[21];
    const float* fw2 = (const float*)d_in[22];
    const float* fb2 = (const float*)d_in[23];

    float* xout     = (float*)d_out;                       // [B,36]
    float* total    = (float*)d_out + (size_t)BTOT * 36;   // scalar
    float* missout  = total + 1;                           // [B,36] as f32 0/1

    float* wsB      = (float*)d_ws;
    short* frags    = (short*)((char*)d_ws + FRAGS_BYTE);
    float* partials = (float*)((char*)d_ws + PART_BYTE);   // [NB,12]

    kp_setup<<<8, 256, 0, stream>>>(
        w1, b1, g1, bt1, m1, v1,
        w2, b2, g2, bt2, m2, v2,
        w3, b3, g3, bt3, m3, v3,
        fw1, fb1, fw2, fb2, wsB, frags);

    kp_main<<<NB, NT, 0, stream>>>(cin, tmask, wsB, frags,
        xout, missout, partials);

    kp_fin<<<1, 256, 0, stream>>>(partials, total);
}

// Round 19
// 55.611 us; speedup vs baseline: 1.2175x; 1.2175x over previous
//
#include <hip/hip_runtime.h>
#include <hip/hip_bf16.h>

#define NB   1024
#define NT   256
#define BTOT 262144   // NB*NT == B

typedef __attribute__((ext_vector_type(8))) short short8;
typedef __attribute__((ext_vector_type(4))) float f32x4;

__device__ __forceinline__ float relu_(float x) { return fmaxf(x, 0.0f); }

// setup-kernel-only (portable RNE)
__device__ __forceinline__ short f2bf(float x) {
    unsigned u = __float_as_uint(x);
    return (short)((u + 0x7FFFu + ((u >> 16) & 1u)) >> 16);
}
__device__ __forceinline__ unsigned pk2bf(float a, float b) {
    return ((unsigned)(unsigned short)f2bf(a)) |
           (((unsigned)(unsigned short)f2bf(b)) << 16);
}

// hot-path conversions: native casts -> HW v_cvt_pk_bf16_f32
__device__ __forceinline__ unsigned pkbf(float a, float b) {
    __hip_bfloat162 h = __float22bfloat162_rn(make_float2(a, b));
    return *(unsigned*)&h;
}
__device__ __forceinline__ void st_bf16(unsigned char* p, float x) {
    *(__hip_bfloat16*)p = __float2bfloat16(x);
}
__device__ __forceinline__ short8 pack8(float a0,float a1,float a2,float a3,
                                        float a4,float a5,float a6,float a7) {
    uint4 v = make_uint4(pkbf(a0,a1), pkbf(a2,a3), pkbf(a4,a5), pkbf(a6,a7));
    return *(short8*)&v;
}

// d_ws byte map:
//  0    : (reserved) | A0 packed bf16 pairs at dword 160
//  768  : 46 B-fragments x 512 shorts (bf16); K-axes PHYSICALLY PERMUTED to
//         writer-thread-contiguous LDS slot order (see per-frag maps below)
//  47872: partials [NB*12] f32
#define A0_DW    160
#define FRAGS_BYTE 768
#define PART_BYTE 47872
#define NFRAG 46

__global__ __launch_bounds__(256) void kp_setup(
    const float* __restrict__ w1, const float* __restrict__ b1,
    const float* __restrict__ g1, const float* __restrict__ bt1,
    const float* __restrict__ m1, const float* __restrict__ v1,
    const float* __restrict__ w2, const float* __restrict__ b2,
    const float* __restrict__ g2, const float* __restrict__ bt2,
    const float* __restrict__ m2, const float* __restrict__ v2,
    const float* __restrict__ w3, const float* __restrict__ b3,
    const float* __restrict__ g3, const float* __restrict__ bt3,
    const float* __restrict__ m3, const float* __restrict__ v3,
    const float* __restrict__ fw1, const float* __restrict__ fb1,
    const float* __restrict__ fw2, const float* __restrict__ fb2,
    float* __restrict__ wsB, short* __restrict__ frags)
{
    __shared__ float w1f[180], b1f[10], a0f[10];
    __shared__ float w2f[400], b2f[20];
    __shared__ float w3f[1200], b3f[30];
    const int t = threadIdx.x;

    if (t < 10) {
        float s = g1[t] * rsqrtf(v1[t] + 1e-5f);
        float bb = (b1[t] - m1[t]) * s + bt1[t];
        b1f[t] = bb; a0f[t] = relu_(bb);
        for (int i = 0; i < 18; ++i) w1f[t * 18 + i] = w1[t * 18 + i] * s;
    } else if (t >= 64 && t < 84) {
        int o = t - 64;
        float s = g2[o] * rsqrtf(v2[o] + 1e-5f);
        b2f[o] = (b2[o] - m2[o]) * s + bt2[o];
        for (int i = 0; i < 20; ++i) w2f[o * 20 + i] = w2[o * 20 + i] * s;
    } else if (t >= 128 && t < 158) {
        int o = t - 128;
        float s = g3[o] * rsqrtf(v3[o] + 1e-5f);
        b3f[o] = (b3[o] - m3[o]) * s + bt3[o];
        for (int i = 0; i < 40; ++i) w3f[o * 40 + i] = w3[o * 40 + i] * s;
    }
    __syncthreads();

    if (blockIdx.x == 0 && t < 5)
        ((unsigned*)wsB)[A0_DW + t] = pk2bf(a0f[2 * t], a0f[2 * t + 1]);

    for (int e = blockIdx.x * 256 + t; e < NFRAG * 512; e += gridDim.x * 256) {
        int frag = e >> 9, l = (e >> 3) & 63, j = e & 7;
        float val = 0.f;
        if (frag < 4) {                       // conv1: logical K (unchanged), N=20
            int p = frag, nt = p >> 1, kt = p & 1;
            int k = kt * 32 + (l >> 4) * 8 + j, n = nt * 16 + (l & 15);
            if (n < 20) {
                int o = n % 10, pp = n / 10;
                if (k < 36) { int i = k >> 1, s = k & 1; if (s == pp) val = w1f[o * 18 + i]; }
                else if (k == 36) val = b1f[o];
            }
        } else if (frag < 12) {               // conv2: a1 PHYSICAL slots
            int p = frag - 4, nt_ = p >> 1, kt = p & 1;
            int kp = kt * 32 + (l >> 4) * 8 + j, n = nt_ * 16 + (l & 15);
            if (n < 60) {
                int lk = -1;
                if (kp < 32) { int s = kp & 1, r = kp >> 1;
                               lk = (s == 0) ? 10 + r : (r < 4 ? 26 + r : -1); }
                else if (kp < 42) lk = kp - 32;
                else if (kp < 52) lk = 30 + (kp - 42);
                else if (kp == 52) lk = 40;
                if (lk >= 0) {
                    int q = n / 20, o = n % 20;
                    if (lk < 40) { int pp = lk / 10, i = lk % 10, d = pp - q;
                                   if (d == 0 || d == 1) val = w2f[o * 20 + i * 2 + d]; }
                    else val = b2f[o];
                }
            }
        } else if (frag < 20) {               // conv3: a2 PHYSICAL p=lrow*4+nt
            int p = frag - 12, nt_ = p >> 1, kt = p & 1;
            int kp = kt * 32 + (l >> 4) * 8 + j, n = nt_ * 16 + (l & 15);
            if (n < 60) {
                int n2 = 16 * (kp & 3) + (kp >> 2);
                int q = n / 30, o = n % 30;
                if (n2 < 60) { int pp = n2 / 20, i = n2 % 20, d = pp - q;
                               if (d == 0 || d == 1) val = w3f[o * 40 + i * 2 + d]; }
                else if (n2 == 60) val = b3f[o];
            }
        } else if (frag < 34) {               // fc1: f PHYSICAL p=lrow*4+nt
            int p = frag - 20, n7 = p >> 1, kt = p & 1;
            int kp = kt * 32 + (l >> 4) * 8 + j, col = n7 * 16 + (l & 15);
            if (col < 100) {
                int n3 = 16 * (kp & 3) + (kp >> 2);
                if (n3 < 60) { int kf = 2 * (n3 % 30) + (n3 / 30);
                               val = fw1[col * 60 + kf]; }
                else if (n3 == 60) val = fb1[col];
            }
        } else {                              // fc2: z PHYSICAL p=lrow*4+nn (per half)
            int p = frag - 34, n3_ = p >> 2, kt = p & 3;
            int kp = kt * 32 + (l >> 4) * 8 + j, col = n3_ * 16 + (l & 15);
            if (col < 36) {
                int jj = 64 * (kp >> 6) + 16 * ((kp & 63) & 3) + ((kp & 63) >> 2);
                if (jj < 100) val = fw2[col * 100 + jj];
                else if (jj == 100) val = fb2[col];
            }
        }
        frags[e] = f2bf(val);
    }
}

__global__ __launch_bounds__(NT) void kp_main(
    const float* __restrict__ cin, const int* __restrict__ tmask,
    const float* __restrict__ wsB, const short* __restrict__ frags,
    float* __restrict__ xout, float* __restrict__ missout,
    float* __restrict__ partials)
{
    // 40960 B total = exactly 4 blocks/CU (LDS-wise)
    __shared__ __align__(16) unsigned char sOUT[NT * 88];       // out rows, bf16
    __shared__ __align__(16) unsigned char sT1[4 * 16 * 144];   // a1 tiles (per-wave)
    __shared__ __align__(16) unsigned char sT2[4 * 16 * 144];   // a2/f/z tiles

    const int t = threadIdx.x;
    const int lane = t & 63, wave = t >> 6;
    const unsigned lrow = (unsigned)(lane & 15);
    const unsigned lkg  = (unsigned)(lane >> 4);
    const unsigned wbase = (unsigned)(t & ~63);
    const short8* frg = (const short8*)frags;

    unsigned char* T1 = sT1 + wave * (16 * 144);
    unsigned char* T2 = sT2 + wave * (16 * 144);

    // ---- one-time: T1 constant region (physical slots 32..63, bytes 64..127)
    //   32..41=A0, 42..51=A0, 52=1.0(bias), 53..63=0
    {
        const unsigned* a0p = (const unsigned*)wsB + A0_DW;
        uint4 A0q = *(const uint4*)a0p;
        unsigned A0e = a0p[4];
        if (lane < 16) {
            unsigned char* b = &T1[(unsigned)lane * 144 + 64];
            *(uint4*)(b +  0) = A0q;
            *(uint4*)(b + 16) = make_uint4(A0e, A0q.x, A0q.y, A0q.z);
            *(uint4*)(b + 32) = make_uint4(A0q.w, A0e, 0x00003F80u, 0u);
            *(uint4*)(b + 48) = make_uint4(0u, 0u, 0u, 0u);
        }
    }

    #pragma unroll 1
    for (int m = 0; m < 4; ++m) {
        const unsigned Rb = wbase + 16u * (unsigned)m;

        // ---- conv1 A-frags straight from global ----
        const float* crow = cin + (size_t)(blockIdx.x * NT + Rb + lrow) * 36;
        float4 qa = *(const float4*)(crow + 8 * lkg);
        float4 qb = *(const float4*)(crow + 8 * lkg + 4);
        float4 qc = *(const float4*)(crow + 32);
        short8 Aa = pack8(qa.x, qa.y, qa.z, qa.w, qb.x, qb.y, qb.z, qb.w);
        float sf = (lkg == 0u) ? 1.f : 0.f;
        short8 Ab = pack8(qc.x * sf, qc.y * sf, qc.z * sf, qc.w * sf, sf, 0.f, 0.f, 0.f);

        // ---- conv1 -> a1 (T1 physical slots 2*lrow, 2*lrow+1; 1 b32/row) ----
        {
            f32x4 D1[2];
            #pragma unroll
            for (int nt = 0; nt < 2; ++nt) {
                D1[nt] = (f32x4){0.f, 0.f, 0.f, 0.f};
                D1[nt] = __builtin_amdgcn_mfma_f32_16x16x32_bf16(Aa, frg[(nt * 2 + 0) * 64 + lane], D1[nt], 0, 0, 0);
                D1[nt] = __builtin_amdgcn_mfma_f32_16x16x32_bf16(Ab, frg[(nt * 2 + 1) * 64 + lane], D1[nt], 0, 0, 0);
            }
            // D1[1] is exactly 0 for lrow>=4 (B cols >=20 are zero) -> no select
            #pragma unroll
            for (int i = 0; i < 4; ++i)
                *(unsigned*)&T1[(4 * lkg + i) * 144 + lrow * 4] =
                    pkbf(relu_(D1[0][i]), relu_(D1[1][i]));
        }

        // ---- conv2: A = a1 (K=64 phys) -> a2 (T2 physical p=lrow*4+nt; 1 b64/row)
        Aa = *(const short8*)&T1[lrow * 144 + lkg * 16u];
        Ab = *(const short8*)&T1[lrow * 144 + 64u + lkg * 16u];
        {
            f32x4 D2[4];
            #pragma unroll
            for (int nt = 0; nt < 4; ++nt) {
                D2[nt] = (f32x4){0.f, 0.f, 0.f, 0.f};
                D2[nt] = __builtin_amdgcn_mfma_f32_16x16x32_bf16(Aa, frg[(4 + nt * 2 + 0) * 64 + lane], D2[nt], 0, 0, 0);
                D2[nt] = __builtin_amdgcn_mfma_f32_16x16x32_bf16(Ab, frg[(4 + nt * 2 + 1) * 64 + lane], D2[nt], 0, 0, 0);
            }
            // slot 51 (lrow==12, nt==3) = K-bias 1.0; lrow>12,nt3 naturally 0
            #pragma unroll
            for (int i = 0; i < 4; ++i) {
                float e3 = (lrow == 12u) ? 1.0f : relu_(D2[3][i]);
                uint2 wv = make_uint2(pkbf(relu_(D2[0][i]), relu_(D2[1][i])),
                                      pkbf(relu_(D2[2][i]), e3));
                *(uint2*)&T2[(4 * lkg + i) * 144 + lrow * 8] = wv;
            }
        }

        // ---- conv3: A = a2 -> f (same physical scheme; 1 b64/row) ----
        Aa = *(const short8*)&T2[lrow * 144 + lkg * 16u];
        Ab = *(const short8*)&T2[lrow * 144 + 64u + lkg * 16u];
        {
            f32x4 D3[4];
            #pragma unroll
            for (int nt = 0; nt < 4; ++nt) {
                D3[nt] = (f32x4){0.f, 0.f, 0.f, 0.f};
                D3[nt] = __builtin_amdgcn_mfma_f32_16x16x32_bf16(Aa, frg[(12 + nt * 2 + 0) * 64 + lane], D3[nt], 0, 0, 0);
                D3[nt] = __builtin_amdgcn_mfma_f32_16x16x32_bf16(Ab, frg[(12 + nt * 2 + 1) * 64 + lane], D3[nt], 0, 0, 0);
            }
            #pragma unroll
            for (int i = 0; i < 4; ++i) {
                float e3 = (lrow == 12u) ? 1.0f : relu_(D3[3][i]);
                uint2 wv = make_uint2(pkbf(relu_(D3[0][i]), relu_(D3[1][i])),
                                      pkbf(relu_(D3[2][i]), e3));
                *(uint2*)&T2[(4 * lkg + i) * 144 + lrow * 8] = wv;
            }
        }

        // ---- fc1 + fc2 (z physical p=lrow*4+nn per 64-slot half; b32 pairs) ----
        short8 Fa = *(const short8*)&T2[lrow * 144 + lkg * 16u];
        short8 Fb = *(const short8*)&T2[lrow * 144 + 64u + lkg * 16u];
        f32x4 acc2[3];
        #pragma unroll
        for (int n = 0; n < 3; ++n) acc2[n] = (f32x4){0.f, 0.f, 0.f, 0.f};

        #pragma unroll
        for (int h = 0; h < 2; ++h) {
            #pragma unroll
            for (int pr = 0; pr < 2; ++pr) {
                const int n0 = 4 * h + 2 * pr;   // <= 6 always
                const int n1 = n0 + 1;           // == 7 only at h=1,pr=1
                f32x4 va = (f32x4){0.f, 0.f, 0.f, 0.f};
                f32x4 vb = (f32x4){0.f, 0.f, 0.f, 0.f};
                va = __builtin_amdgcn_mfma_f32_16x16x32_bf16(Fa, frg[(20 + n0 * 2 + 0) * 64 + lane], va, 0, 0, 0);
                va = __builtin_amdgcn_mfma_f32_16x16x32_bf16(Fb, frg[(20 + n0 * 2 + 1) * 64 + lane], va, 0, 0, 0);
                if (n1 < 7) {
                    vb = __builtin_amdgcn_mfma_f32_16x16x32_bf16(Fa, frg[(20 + n1 * 2 + 0) * 64 + lane], vb, 0, 0, 0);
                    vb = __builtin_amdgcn_mfma_f32_16x16x32_bf16(Fb, frg[(20 + n1 * 2 + 1) * 64 + lane], vb, 0, 0, 0);
                }
                #pragma unroll
                for (int i = 0; i < 4; ++i) {
                    float z0 = relu_(va[i]);
                    if (h == 1 && pr == 1 && lrow == 4u) z0 = 1.0f;  // z[100]=bias
                    float z1 = (n1 < 7) ? relu_(vb[i]) : 0.f;
                    *(unsigned*)&T2[(4 * lkg + i) * 144 + lrow * 8 + 4 * pr] =
                        pkbf(z0, z1);
                }
            }
            #pragma unroll
            for (int q = 0; q < 2; ++q) {
                const int kt = 2 * h + q;
                short8 Az = *(const short8*)&T2[lrow * 144 + (unsigned)(q * 64) + lkg * 16u];
                #pragma unroll
                for (int n = 0; n < 3; ++n)
                    acc2[n] = __builtin_amdgcn_mfma_f32_16x16x32_bf16(Az, frg[(34 + n * 4 + kt) * 64 + lane], acc2[n], 0, 0, 0);
            }
        }

        // out (bf16) -> sOUT rows of this tile
        #pragma unroll
        for (int n = 0; n < 3; ++n) {
            const int col = 16 * n + (int)lrow;
            if (col < 36) {
                #pragma unroll
                for (int i = 0; i < 4; ++i)
                    st_bf16(&sOUT[(Rb + 4 * lkg + i) * 88 + col * 2],
                            acc2[n][i]);
            }
        }
    }

    // ---- part losses, minimal live set: on-demand loads ----
    const float* cp = cin + (size_t)(blockIdx.x * NT + t) * 36;
    float sp[5], np[5];
    {   // head (0,14,15); gt mixes x[:,15,0] and c[:,15,1] (faithful)
        unsigned w0  = *(const unsigned*)&sOUT[t * 88 + 0];
        unsigned w28 = *(const unsigned*)&sOUT[t * 88 + 56];
        unsigned w30 = *(const unsigned*)&sOUT[t * 88 + 60];
        float o0x = __uint_as_float(w0 << 16),  o0y = __uint_as_float(w0 & 0xFFFF0000u);
        float o28 = __uint_as_float(w28 << 16), o29 = __uint_as_float(w28 & 0xFFFF0000u);
        float o30 = __uint_as_float(w30 << 16), o31 = __uint_as_float(w30 & 0xFFFF0000u);
        float2 c0  = *(const float2*)(cp + 0);
        float2 c28 = *(const float2*)(cp + 28);
        float2 c30 = *(const float2*)(cp + 30);
        float dxa = o0x - o28, dya = o0y - o29;
        float dxb = o0x - o30, dyb = o0y - o31;
        float pred = 0.5f * (sqrtf(dxa*dxa + dya*dya) + sqrtf(dxb*dxb + dyb*dyb));
        float cxa = c0.x - c28.x, cya = c0.y - c28.y;
        float gxa = c0.x - o30,   gya = c0.y - c30.y;
        float gt = 0.5f * (sqrtf(cxa*cxa + cya*cya) + sqrtf(gxa*gxa + gya*gya));
        float vf = (c0.x != -1.f && c28.x != -1.f && c30.x != -1.f) ? 1.f : 0.f;
        float e = pred - gt;
        sp[0] = e * e * vf; np[0] = vf;
    }
    #pragma unroll
    for (int p = 0; p < 4; ++p) {
        const int a = 2 + 3 * p;   // b=a+1, cc=a+2
        unsigned wA = *(const unsigned*)&sOUT[t * 88 + 4 * a + 0];
        unsigned wB = *(const unsigned*)&sOUT[t * 88 + 4 * a + 4];
        unsigned wC = *(const unsigned*)&sOUT[t * 88 + 4 * a + 8];
        float oax = __uint_as_float(wA << 16), oay = __uint_as_float(wA & 0xFFFF0000u);
        float obx = __uint_as_float(wB << 16), oby = __uint_as_float(wB & 0xFFFF0000u);
        float ocx = __uint_as_float(wC << 16), ocy = __uint_as_float(wC & 0xFFFF0000u);
        float2 ca = *(const float2*)(cp + 2 * a);
        float2 cb = *(const float2*)(cp + 2 * a + 2);
        float2 cc2 = *(const float2*)(cp + 2 * a + 4);
        float dxa = oax - obx, dya = oay - oby;
        float dxb = obx - ocx, dyb = oby - ocy;
        float pred = 0.5f * (sqrtf(dxa*dxa + dya*dya) + sqrtf(dxb*dxb + dyb*dyb));
        float cxa = ca.x - cb.x, cya = ca.y - cb.y;
        float gxa = cb.x - ocx,  gya = cb.y - cc2.y;
        float gt = 0.5f * (sqrtf(cxa*cxa + cya*cya) + sqrtf(gxa*gxa + gya*gya));
        float vf = (ca.x != -1.f && cb.x != -1.f && cc2.x != -1.f) ? 1.f : 0.f;
        float e = pred - gt;
        sp[p + 1] = e * e * vf; np[p + 1] = vf;
    }

    __syncthreads();   // all waves' out-rows complete

    // ---- coalesced x store + miss store + elementwise kp-loss ----
    const size_t blkBase = (size_t)blockIdx.x * (NT * 36);
    const float4* cin4 = (const float4*)(cin + blkBase);
    const int4*   tm4  = (const int4*)(tmask + blkBase);
    float4*       x4   = (float4*)(xout + blkBase);
    float*        mo   = missout + blkBase;

    float s1 = 0.f, s2 = 0.f;
    #pragma unroll
    for (int i = 0; i < 9; ++i) {
        int g4 = i * NT + t;
        unsigned g = 4u * (unsigned)g4;
        unsigned row = g / 36u;
        unsigned col = g - row * 36u;          // col % 4 == 0 -> 8B aligned
        uint2 w = *(const uint2*)&sOUT[row * 88u + col * 2u];
        float4 xv;
        xv.x = __uint_as_float(w.x << 16);
        xv.y = __uint_as_float(w.x & 0xFFFF0000u);
        xv.z = __uint_as_float(w.y << 16);
        xv.w = __uint_as_float(w.y & 0xFFFF0000u);
        float4 cv = cin4[g4];
        int4   mv = tm4[g4];
        x4[g4] = xv;
        mo[g + 0] = (cv.x != -1.f) ? 1.f : 0.f;
        mo[g + 1] = (cv.y != -1.f) ? 1.f : 0.f;
        mo[g + 2] = (cv.z != -1.f) ? 1.f : 0.f;
        mo[g + 3] = (cv.w != -1.f) ? 1.f : 0.f;
        float m0 = (float)mv.x, m1_ = (float)mv.y, m2_ = (float)mv.z, m3_ = (float)mv.w;
        float d0 = xv.x - cv.x, d1 = xv.y - cv.y, d2 = xv.z - cv.z, d3 = xv.w - cv.w;
        s1 += d0*d0*m0 + d1*d1*m1_ + d2*d2*m2_ + d3*d3*m3_;
        s2 += m0 + m1_ + m2_ + m3_;
    }

    // ---- block reduction of 12 scalars (scratch = dead sT1 region) ----
    float rv[12] = { s1, s2, sp[0], np[0], sp[1], np[1],
                     sp[2], np[2], sp[3], np[3], sp[4], np[4] };
    #pragma unroll
    for (int v = 0; v < 12; ++v) {
        #pragma unroll
        for (int off = 32; off > 0; off >>= 1)
            rv[v] += __shfl_down(rv[v], off, 64);
    }
    if (lane == 0) {
        float* sw = (float*)(sT1 + wave * (16 * 144));
        #pragma unroll
        for (int v = 0; v < 12; ++v) sw[v] = rv[v];
    }
    __syncthreads();
    if (t < 12) {
        float s = 0.f;
        #pragma unroll
        for (int w = 0; w < 4; ++w) s += ((const float*)(sT1 + w * (16 * 144)))[t];
        partials[blockIdx.x * 12 + t] = s;
    }
}

__global__ __launch_bounds__(256) void kp_fin(const float* __restrict__ partials,
                                              float* __restrict__ total_out)
{
    __shared__ float sred[4][12];
    const int t = threadIdx.x;
    float rv[12];
    #pragma unroll
    for (int v = 0; v < 12; ++v) rv[v] = 0.f;
    for (int b = t; b < NB; b += 256) {
        #pragma unroll
        for (int v = 0; v < 12; ++v) rv[v] += partials[b * 12 + v];
    }
    #pragma unroll
    for (int v = 0; v < 12; ++v) {
        #pragma unroll
        for (int off = 32; off > 0; off >>= 1)
            rv[v] += __shfl_down(rv[v], off, 64);
    }
    const int wave = t >> 6, lane = t & 63;
    if (lane == 0) {
        #pragma unroll
        for (int v = 0; v < 12; ++v) sred[wave][v] = rv[v];
    }
    __syncthreads();
    if (t == 0) {
        float acc[12];
        #pragma unroll
        for (int v = 0; v < 12; ++v)
            acc[v] = sred[0][v] + sred[1][v] + sred[2][v] + sred[3][v];
        float total = acc[0] / acc[1];
        #pragma unroll
        for (int p = 0; p < 5; ++p) {
            float s = acc[2 + 2 * p], n = acc[3 + 2 * p];
            total += (n > 0.f) ? (s / fmaxf(n, 1.f)) : 0.f;
        }
        total_out[0] = total;
    }
}

extern "C" void kernel_launch(void* const* d_in, const int* in_sizes, int n_in,
                              void* d_out, int out_size, void* d_ws, size_t ws_size,
                              hipStream_t stream)
{
    const float* cin   = (const float*)d_in[0];
    const int*   tmask = (const int*)  d_in[1];
    const float* w1  = (const float*)d_in[2];
    const float* b1  = (const float*)d_in[3];
    const float* g1  = (const float*)d_in[4];
    const float* bt1 = (const float*)d_in[5];
    const float* m1  = (const float*)d_in[6];
    const float* v1  = (const float*)d_in[7];
    const float* w2  = (const float*)d_in[8];
    const float* b2  = (const float*)d_in[9];
    const float* g2  = (const float*)d_in[10];
    const float* bt2 = (const float*)d_in[11];
    const float* m2  = (const float*)d_in[12];
    const float* v2  = (const float*)d_in[13];
    const float* w3  = (const float*)d_in[14];
    const float* b3  = (const float*)d_in[15];
    const float* g3  = (const float*)d_in[16];
    const float* bt3 = (const float*)d_in[17];
    const float* m3  = (const float*)d_in[18];
    const float* v3  = (const float*)d_in[19];
    const float* fw1 = (const float*)d_in[20];
    const float* fb1 = (const float*)d_in[21];
    const float* fw2 = (const float*)d_in[22];
    const float* fb2 = (const float*)d_in[23];

    float* xout     = (float*)d_out;                       // [B,36]
    float* total    = (float*)d_out + (size_t)BTOT * 36;   // scalar
    float* missout  = total + 1;                           // [B,36] as f32 0/1

    float* wsB      = (float*)d_ws;
    short* frags    = (short*)((char*)d_ws + FRAGS_BYTE);
    float* partials = (float*)((char*)d_ws + PART_BYTE);   // [NB,12]

    kp_setup<<<8, 256, 0, stream>>>(
        w1, b1, g1, bt1, m1, v1,
        w2, b2, g2, bt2, m2, v2,
        w3, b3, g3, bt3, m3, v3,
        fw1, fb1, fw2, fb2, wsB, frags);

    kp_main<<<NB, NT, 0, stream>>>(cin, tmask, wsB, frags,
        xout, missout, partials);

    kp_fin<<<1, 256, 0, stream>>>(partials, total);
}